// Round 4
// baseline (4702.312 us; speedup 1.0000x reference)
//
#include <hip/hip_runtime.h>
#include <hip/hip_bf16.h>

#define BN_EPS 1e-4f

__device__ __forceinline__ int rfl(int x) { return __builtin_amdgcn_readfirstlane(x); }

__device__ __forceinline__ float ldf(const float* p) { return *p; }
__device__ __forceinline__ float ldf(const __hip_bfloat16* p) { return __bfloat162float(*p); }
__device__ __forceinline__ void stf(float* p, float v) { *p = v; }
__device__ __forceinline__ void stf(__hip_bfloat16* p, float v) { *p = __float2bfloat16(v); }

// ---------------- xv = subconv(feats[N,3], nbr_fine, W_sub[27,3,32]) ----------------
__global__ __launch_bounds__(256) void k_xv(const float* __restrict__ feats,
                                            const int* __restrict__ nbr,
                                            const float* __restrict__ W,
                                            float* __restrict__ out, int N) {
    int n = blockIdx.x * 256 + threadIdx.x;
    if (n >= N) return;
    float acc[32];
#pragma unroll
    for (int d = 0; d < 32; ++d) acc[d] = 0.f;
    const int* nb = nbr + (size_t)n * 27;
    for (int k = 0; k < 27; ++k) {
        int idx = nb[k];
        if (idx < 0) continue;
        float f0 = feats[(size_t)idx * 3 + 0];
        float f1 = feats[(size_t)idx * 3 + 1];
        float f2 = feats[(size_t)idx * 3 + 2];
        const float* w = W + k * 96;  // k uniform -> scalar loads
#pragma unroll
        for (int d = 0; d < 32; ++d)
            acc[d] += f0 * w[d] + f1 * w[32 + d] + f2 * w[64 + d];
    }
    float4* o = (float4*)(out + (size_t)n * 32);
#pragma unroll
    for (int j = 0; j < 8; ++j)
        o[j] = make_float4(acc[4 * j], acc[4 * j + 1], acc[4 * j + 2], acc[4 * j + 3]);
}

// ---------------- LDS-staged row-blocked submanifold conv ----------------
// Workgroup = 4 waves; each wave owns RB=16 consecutive rows (64 rows/wg).
// Per tap k: 256 threads stage W[k] (CIN x COUT fp32) into LDS once, barrier;
// each wave ballots validity of its 16 rows (wave-uniform skip), gathers the
// 16 neighbor feature rows back-to-back (deep MLP hides gather latency), then
// applies weights in 4-register chunks hoisted out of the row loop (LDS reads
// per tap, not per row). acc[16] float4 stays in VGPRs; launch_bounds(256,3)
// caps VGPR ~168 -> no scratch spill (R3's 2.2 GB WRITE_SIZE lesson).
// lane = split*(COUT/4) + d4; cross-split shfl_xor reduction at the end.
template <int CIN, int COUT, bool SPLIT, typename TIN, typename TOUT>
__global__ __launch_bounds__(256, 3) void k_subconv(const TIN* __restrict__ inA,
                                                    const TIN* __restrict__ inB,
                                                    const int* __restrict__ nbr,
                                                    const float* __restrict__ W,
                                                    TOUT* __restrict__ out, int nrows,
                                                    float* __restrict__ ssum,
                                                    float* __restrict__ ssq) {
    constexpr int RB = 16;            // rows per wave
    constexpr int DQ = COUT / 4;      // float4 output groups
    constexpr int NSPLIT = 64 / DQ;   // c-chunks
    constexpr int CCH = CIN / NSPLIT; // c per chunk (4, 8, or 16)
    __shared__ float smem[CIN * COUT];
    const int tid = threadIdx.x;
    const int lane = tid & 63;
    const int wv = tid >> 6;
    const int split = lane / DQ;
    const int d4 = lane % DQ;
    const int nblk64 = (nrows + 63) / 64;
    float s0 = 0.f, s1 = 0.f, s2 = 0.f, s3 = 0.f;
    float q0 = 0.f, q1 = 0.f, q2 = 0.f, q3 = 0.f;
    for (int blk = blockIdx.x; blk < nblk64; blk += gridDim.x) {
        const int row0 = blk * 64 + wv * RB;  // this wave's first row
        int nr = nrows - row0;
        nr = nr < 0 ? 0 : (nr > RB ? RB : nr);
        float4 acc[RB];
#pragma unroll
        for (int r = 0; r < RB; ++r) acc[r] = make_float4(0.f, 0.f, 0.f, 0.f);
        for (int k = 0; k < 27; ++k) {
            // ---- cooperative stage: W[k] tile -> LDS ----
            {
                const float4* Wg = (const float4*)(W + (size_t)k * CIN * COUT);
                float4* sm4 = (float4*)smem;
#pragma unroll
                for (int i = 0; i < CIN * COUT / 1024; ++i)
                    sm4[tid + i * 256] = Wg[tid + i * 256];
            }
            __syncthreads();
            // ---- per-wave compute (skippable; all threads reach barrier 2) ----
            int idx = (lane < nr) ? nbr[(size_t)(row0 + lane) * 27 + k] : -1;
            unsigned long long m = __ballot(idx >= 0);
            if (m) {
                // pass 1: issue all gathers (independent -> overlapped)
                float f[RB];
#pragma unroll
                for (int r = 0; r < RB; ++r) {
                    f[r] = 0.f;
                    if (m & (1ull << r)) {
                        int ir = __shfl(idx, r);
                        if (SPLIT)
                            f[r] = (lane < 32) ? ldf(inA + (size_t)ir * 32 + lane)
                                               : ldf(inB + (size_t)ir * 32 + lane - 32);
                        else
                            f[r] = (CIN == 64 || lane < CIN)
                                       ? ldf(inA + (size_t)ir * CIN + lane) : 0.f;
                    }
                }
                // pass 2: weight chunks (4 float4 regs) applied to all rows
#pragma unroll
                for (int c = 0; c < CCH / 4; ++c) {
                    const float4* ws =
                        (const float4*)(smem + ((size_t)(split * CCH + c * 4)) * COUT) + d4;
                    float4 w0 = ws[0 * DQ], w1 = ws[1 * DQ], w2 = ws[2 * DQ], w3 = ws[3 * DQ];
#pragma unroll
                    for (int r = 0; r < RB; ++r) {
                        if (!(m & (1ull << r))) continue;  // uniform row skip
                        float v0 = __shfl(f[r], split * CCH + c * 4 + 0);
                        float v1 = __shfl(f[r], split * CCH + c * 4 + 1);
                        float v2 = __shfl(f[r], split * CCH + c * 4 + 2);
                        float v3 = __shfl(f[r], split * CCH + c * 4 + 3);
                        acc[r].x = fmaf(v0, w0.x, acc[r].x);
                        acc[r].y = fmaf(v0, w0.y, acc[r].y);
                        acc[r].z = fmaf(v0, w0.z, acc[r].z);
                        acc[r].w = fmaf(v0, w0.w, acc[r].w);
                        acc[r].x = fmaf(v1, w1.x, acc[r].x);
                        acc[r].y = fmaf(v1, w1.y, acc[r].y);
                        acc[r].z = fmaf(v1, w1.z, acc[r].z);
                        acc[r].w = fmaf(v1, w1.w, acc[r].w);
                        acc[r].x = fmaf(v2, w2.x, acc[r].x);
                        acc[r].y = fmaf(v2, w2.y, acc[r].y);
                        acc[r].z = fmaf(v2, w2.z, acc[r].z);
                        acc[r].w = fmaf(v2, w2.w, acc[r].w);
                        acc[r].x = fmaf(v3, w3.x, acc[r].x);
                        acc[r].y = fmaf(v3, w3.y, acc[r].y);
                        acc[r].z = fmaf(v3, w3.z, acc[r].z);
                        acc[r].w = fmaf(v3, w3.w, acc[r].w);
                    }
                }
            }
            __syncthreads();  // protect LDS before next tap's stage
        }
        // ---- cross-split reduction + store + BN stats ----
#pragma unroll
        for (int r = 0; r < RB; ++r) {
            if (r >= nr) break;
            float ax = acc[r].x, ay = acc[r].y, az = acc[r].z, aw = acc[r].w;
#pragma unroll
            for (int off = DQ; off < 64; off <<= 1) {
                ax += __shfl_xor(ax, off);
                ay += __shfl_xor(ay, off);
                az += __shfl_xor(az, off);
                aw += __shfl_xor(aw, off);
            }
            if (split == 0) {
                TOUT* ob = out + (size_t)(row0 + r) * COUT + d4 * 4;
                stf(ob + 0, ax); stf(ob + 1, ay); stf(ob + 2, az); stf(ob + 3, aw);
                s0 += ax; s1 += ay; s2 += az; s3 += aw;
                q0 += ax * ax; q1 += ay * ay; q2 += az * az; q3 += aw * aw;
            }
        }
    }
    if (split == 0) {
        atomicAdd(&ssum[d4 * 4 + 0], s0);
        atomicAdd(&ssum[d4 * 4 + 1], s1);
        atomicAdd(&ssum[d4 * 4 + 2], s2);
        atomicAdd(&ssum[d4 * 4 + 3], s3);
        atomicAdd(&ssq[d4 * 4 + 0], q0);
        atomicAdd(&ssq[d4 * 4 + 1], q1);
        atomicAdd(&ssq[d4 * 4 + 2], q2);
        atomicAdd(&ssq[d4 * 4 + 3], q3);
    }
}

// ---------------- BN finalize: scale/shift from sums ----------------
__global__ void k_fin(const float* __restrict__ ssum, const float* __restrict__ ssq,
                      const float* __restrict__ g, const float* __restrict__ b,
                      float* __restrict__ scale, float* __restrict__ shift,
                      int C, float invN) {
    int c = blockIdx.x * blockDim.x + threadIdx.x;
    if (c >= C) return;
    float mu = ssum[c] * invN;
    float var = fmaxf(ssq[c] * invN - mu * mu, 0.f);
    float s = g[c] * rsqrtf(var + BN_EPS);
    scale[c] = s;
    shift[c] = b[c] - mu * s;
}

// ---- e0 = bnrelu(e0raw) in place (bf16); down[parent] += e0 @ W_down[off] (fp32 atomics) ----
__global__ __launch_bounds__(256) void k_down(__hip_bfloat16* __restrict__ e0,
                                              const int* __restrict__ parent,
                                              const int* __restrict__ child,
                                              const float* __restrict__ Wd,
                                              const float* __restrict__ sc,
                                              const float* __restrict__ sh,
                                              float* __restrict__ down, int N) {
    const int lane = threadIdx.x & 63;
    int wid = blockIdx.x * 4 + (threadIdx.x >> 6);
    int nw = gridDim.x * 4;
    for (int row = wid; row < N; row += nw) {
        int urow = rfl(row);
        float v = 0.f;
        if (lane < 32) {
            float r = ldf(e0 + (size_t)urow * 32 + lane);
            v = fmaxf(fmaf(r, sc[lane], sh[lane]), 0.f);
            stf(e0 + (size_t)urow * 32 + lane, v);  // post-BN e0, consumed by dec
        }
        int par = rfl(parent[urow]);
        int off = rfl(child[urow]);
        float acc = 0.f;
        const float* wb = Wd + (size_t)off * 2048 + lane;  // W_down[off][c][lane]
#pragma unroll
        for (int c = 0; c < 32; ++c)
            acc = fmaf(__shfl(v, c), wb[c * 64], acc);
        atomicAdd(&down[(size_t)par * 64 + lane], acc);
    }
}

// ---- up[n] = bnrelu(e1raw)[parent[n]] @ W_up[off[n]] -> bf16 ----
__global__ __launch_bounds__(256) void k_up(const __hip_bfloat16* __restrict__ e1raw,
                                            const int* __restrict__ parent,
                                            const int* __restrict__ child,
                                            const float* __restrict__ Wu,
                                            const float* __restrict__ sc,
                                            const float* __restrict__ sh,
                                            __hip_bfloat16* __restrict__ up, int N) {
    const int lane = threadIdx.x & 63;
    int wid = blockIdx.x * 4 + (threadIdx.x >> 6);
    int nw = gridDim.x * 4;
    for (int row = wid; row < N; row += nw) {
        int urow = rfl(row);
        int par = rfl(parent[urow]);
        int off = rfl(child[urow]);
        float e = ldf(e1raw + (size_t)par * 64 + lane);
        float v = fmaxf(fmaf(e, sc[lane], sh[lane]), 0.f);  // BN on the fly
        int d = lane & 31, hi = lane >> 5;
        float acc = 0.f;
        const float* wb = Wu + (size_t)off * 2048 + (size_t)hi * 1024 + d;
#pragma unroll
        for (int c = 0; c < 32; ++c)
            acc = fmaf(__shfl(v, hi * 32 + c), wb[c * 32], acc);
        acc += __shfl_xor(acc, 32);
        if (hi == 0) stf(up + (size_t)urow * 32 + d, acc);
    }
}

// ---- feature = bnrelu(decraw); y = feature @ W_lin + b_lin ----
__global__ __launch_bounds__(256) void k_out(const __hip_bfloat16* __restrict__ dec,
                                             const float* __restrict__ sc,
                                             const float* __restrict__ sh,
                                             const float* __restrict__ Wl,
                                             const float* __restrict__ bl,
                                             float* __restrict__ y,
                                             float* __restrict__ feat, int N) {
    int n = blockIdx.x * 256 + threadIdx.x;
    if (n >= N) return;
    float f[32];
    const __hip_bfloat162* p = (const __hip_bfloat162*)(dec + (size_t)n * 32);
#pragma unroll
    for (int j = 0; j < 16; ++j) {
        float2 t = __bfloat1622float2(p[j]);
        f[2 * j + 0] = fmaxf(fmaf(t.x, sc[2 * j + 0], sh[2 * j + 0]), 0.f);
        f[2 * j + 1] = fmaxf(fmaf(t.y, sc[2 * j + 1], sh[2 * j + 1]), 0.f);
    }
    float4* fo = (float4*)(feat + (size_t)n * 32);
#pragma unroll
    for (int j = 0; j < 8; ++j)
        fo[j] = make_float4(f[4 * j], f[4 * j + 1], f[4 * j + 2], f[4 * j + 3]);
    float acc[20];
#pragma unroll
    for (int q = 0; q < 20; ++q) acc[q] = bl[q];
#pragma unroll
    for (int c = 0; c < 32; ++c) {
        float fc = f[c];
#pragma unroll
        for (int q = 0; q < 20; ++q) acc[q] = fmaf(fc, Wl[c * 20 + q], acc[q]);
    }
    float4* yo = (float4*)(y + (size_t)n * 20);
#pragma unroll
    for (int j = 0; j < 5; ++j)
        yo[j] = make_float4(acc[4 * j], acc[4 * j + 1], acc[4 * j + 2], acc[4 * j + 3]);
}

extern "C" void kernel_launch(void* const* d_in, const int* in_sizes, int n_in,
                              void* d_out, int out_size, void* d_ws, size_t ws_size,
                              hipStream_t stream) {
    const float* feats = (const float*)d_in[0];
    const int* nbr_f   = (const int*)d_in[1];
    const int* nbr_c   = (const int*)d_in[2];
    const int* parent  = (const int*)d_in[3];
    const int* child   = (const int*)d_in[4];
    const float* W_sub = (const float*)d_in[5];
    const float* W_e0  = (const float*)d_in[6];
    const float* g0    = (const float*)d_in[7];
    const float* b0    = (const float*)d_in[8];
    const float* W_dn  = (const float*)d_in[9];
    const float* W_e1  = (const float*)d_in[10];
    const float* g1    = (const float*)d_in[11];
    const float* b1    = (const float*)d_in[12];
    const float* W_up  = (const float*)d_in[13];
    const float* W_dec = (const float*)d_in[14];
    const float* g_o   = (const float*)d_in[15];
    const float* b_o   = (const float*)d_in[16];
    const float* W_lin = (const float*)d_in[17];
    const float* b_lin = (const float*)d_in[18];

    const int N = in_sizes[0] / 3;
    const int M = in_sizes[2] / 27;

    // --- workspace (~94.3 MB): overlapped live ranges ---
    // [0 .. R): xv fp32 (N*32, steps 1-2)  /  down fp32 (M*64, steps 4-5)
    //           up bf16 at [0..N*16) + decraw bf16 at [N*16..N*32) (steps 7-10)
    // [R .. R+512): BN stats
    float* wsf = (float*)d_ws;
    size_t R = (size_t)M * 64;
    if ((size_t)N * 32 > R) R = (size_t)N * 32;
    float* xv   = wsf;
    float* down = wsf;
    __hip_bfloat16* up     = (__hip_bfloat16*)wsf;
    __hip_bfloat16* decraw = (__hip_bfloat16*)(wsf + (size_t)N * 16);
    float* stats = wsf + R;
    // stats map: 0 sum0[32] | 32 sq0[32] | 64 sum1[64] | 128 sq1[64] |
    //            192 sumo[32] | 224 sqo[32] | 256 scale0 | 288 shift0 |
    //            320 scale1[64] | 384 shift1[64] | 448 scaleo | 480 shifto

    // --- d_out doubles as scratch: e0 bf16 [0..N*16 floats), e1raw bf16
    // [N*16..N*16+M*32); both dead before k_out writes y/feat (M <= N). ---
    __hip_bfloat16* e0    = (__hip_bfloat16*)d_out;
    __hip_bfloat16* e1raw = (__hip_bfloat16*)((float*)d_out + (size_t)N * 16);
    float* y    = (float*)d_out;
    float* feat = y + (size_t)N * 20;

    const int nblk = (N + 255) / 256;
    const int G = 2048;

    hipMemsetAsync(stats, 0, 256 * sizeof(float), stream);

    k_xv<<<nblk, 256, 0, stream>>>(feats, nbr_f, W_sub, xv, N);
    k_subconv<32, 32, false, float, __hip_bfloat16>
        <<<G, 256, 0, stream>>>(xv, nullptr, nbr_f, W_e0, e0, N,
                                stats + 0, stats + 32);
    // xv dead; zero `down` (same region) for the atomic segment-sum
    hipMemsetAsync(down, 0, (size_t)M * 64 * sizeof(float), stream);
    k_fin<<<1, 64, 0, stream>>>(stats + 0, stats + 32, g0, b0,
                                stats + 256, stats + 288, 32, 1.f / (float)N);
    k_down<<<G, 256, 0, stream>>>(e0, parent, child, W_dn,
                                  stats + 256, stats + 288, down, N);
    k_subconv<64, 64, false, float, __hip_bfloat16>
        <<<G, 256, 0, stream>>>(down, nullptr, nbr_c, W_e1, e1raw, M,
                                stats + 64, stats + 128);
    k_fin<<<1, 64, 0, stream>>>(stats + 64, stats + 128, g1, b1,
                                stats + 320, stats + 384, 64, 1.f / (float)M);
    k_up<<<G, 256, 0, stream>>>(e1raw, parent, child, W_up,
                                stats + 320, stats + 384, up, N);
    k_subconv<64, 32, true, __hip_bfloat16, __hip_bfloat16>
        <<<G, 256, 0, stream>>>(e0, up, nbr_f, W_dec, decraw, N,
                                stats + 192, stats + 224);
    k_fin<<<1, 64, 0, stream>>>(stats + 192, stats + 224, g_o, b_o,
                                stats + 448, stats + 480, 32, 1.f / (float)N);
    k_out<<<nblk, 256, 0, stream>>>(decraw, stats + 448, stats + 480, W_lin, b_lin,
                                    y, feat, N);
}

// Round 5
// 4087.078 us; speedup vs baseline: 1.1505x; 1.1505x over previous
//
#include <hip/hip_runtime.h>
#include <hip/hip_bf16.h>

#define BN_EPS 1e-4f

__device__ __forceinline__ int rfl(int x) { return __builtin_amdgcn_readfirstlane(x); }

__device__ __forceinline__ float ldf(const float* p) { return *p; }
__device__ __forceinline__ float ldf(const __hip_bfloat16* p) { return __bfloat162float(*p); }
__device__ __forceinline__ void stf(float* p, float v) { *p = v; }
__device__ __forceinline__ void stf(__hip_bfloat16* p, float v) { *p = __float2bfloat16(v); }

// ---------------- xv = subconv(feats[N,3], nbr_fine, W_sub[27,3,32]) ----------------
__global__ __launch_bounds__(256) void k_xv(const float* __restrict__ feats,
                                            const int* __restrict__ nbr,
                                            const float* __restrict__ W,
                                            float* __restrict__ out, int N) {
    int n = blockIdx.x * 256 + threadIdx.x;
    if (n >= N) return;
    float acc[32];
#pragma unroll
    for (int d = 0; d < 32; ++d) acc[d] = 0.f;
    const int* nb = nbr + (size_t)n * 27;
    for (int k = 0; k < 27; ++k) {
        int idx = nb[k];
        if (idx < 0) continue;
        float f0 = feats[(size_t)idx * 3 + 0];
        float f1 = feats[(size_t)idx * 3 + 1];
        float f2 = feats[(size_t)idx * 3 + 2];
        const float* w = W + k * 96;  // k uniform -> scalar loads
#pragma unroll
        for (int d = 0; d < 32; ++d)
            acc[d] += f0 * w[d] + f1 * w[32 + d] + f2 * w[64 + d];
    }
    float4* o = (float4*)(out + (size_t)n * 32);
#pragma unroll
    for (int j = 0; j < 8; ++j)
        o[j] = make_float4(acc[4 * j], acc[4 * j + 1], acc[4 * j + 2], acc[4 * j + 3]);
}

// ---------------- row-blocked streaming-weight submanifold conv ----------------
// R2 structure + RB=8 rows per wave. Weight chunks stream ONE float4 at a time
// (i-outer loop, only ~1 weight reg live -> no spill; R3/R4 lesson) but each
// loaded chunk is applied to all valid rows of the block -> L2 weight traffic
// divided by valid-rows-per-tap (~2.9 coarse / ~2.3 fine). Gathers for the 8
// rows issue back-to-back (MLP hides L3 latency). Tap/row skips are scalar
// branches on the ballot mask (wave-uniform).
// lane = split*(COUT/4) + d4; cross-split shfl_xor reduction; BN stats fp32.
template <int CIN, int COUT, int RB, bool SPLIT, typename TIN, typename TOUT>
__global__ __launch_bounds__(256) void k_subconv(const TIN* __restrict__ inA,
                                                 const TIN* __restrict__ inB,
                                                 const int* __restrict__ nbr,
                                                 const float* __restrict__ W,
                                                 TOUT* __restrict__ out, int nrows,
                                                 float* __restrict__ ssum,
                                                 float* __restrict__ ssq) {
    constexpr int DQ = COUT / 4;      // float4 output groups
    constexpr int NSPLIT = 64 / DQ;   // c-chunks
    constexpr int CCH = CIN / NSPLIT; // c per chunk
    const int lane = threadIdx.x & 63;
    const int split = lane / DQ;
    const int d4 = lane % DQ;
    int wid = blockIdx.x * 4 + (threadIdx.x >> 6);
    int nw = gridDim.x * 4;
    const int nblkrows = (nrows + RB - 1) / RB;
    float s0 = 0.f, s1 = 0.f, s2 = 0.f, s3 = 0.f;
    float q0 = 0.f, q1 = 0.f, q2 = 0.f, q3 = 0.f;
    for (int blk = wid; blk < nblkrows; blk += nw) {
        const int row0 = rfl(blk) * RB;
        int nr = nrows - row0;
        nr = nr > RB ? RB : nr;
        float4 acc[RB];
#pragma unroll
        for (int r = 0; r < RB; ++r) acc[r] = make_float4(0.f, 0.f, 0.f, 0.f);
        for (int k = 0; k < 27; ++k) {
            int idx = (lane < nr) ? nbr[(size_t)(row0 + lane) * 27 + k] : -1;
            unsigned long long m = __ballot(idx >= 0);
            if (!m) continue;  // wave-uniform tap skip
            // pass 1: all gathers issued back-to-back (independent)
            float f[RB];
#pragma unroll
            for (int r = 0; r < RB; ++r) {
                f[r] = 0.f;
                if (m & (1ull << r)) {
                    int ir = __shfl(idx, r);
                    if (SPLIT)
                        f[r] = (lane < 32) ? ldf(inA + (size_t)ir * 32 + lane)
                                           : ldf(inB + (size_t)ir * 32 + lane - 32);
                    else
                        f[r] = (CIN == 64 || lane < CIN)
                                   ? ldf(inA + (size_t)ir * CIN + lane) : 0.f;
                }
            }
            // pass 2: stream weight chunks, one float4 live, reused across rows
            const float4* w4 =
                (const float4*)(W + ((size_t)k * CIN + split * CCH) * COUT) + d4;
#pragma unroll
            for (int i = 0; i < CCH; ++i) {
                float4 w = w4[i * DQ];
#pragma unroll
                for (int r = 0; r < RB; ++r) {
                    if (!(m & (1ull << r))) continue;  // uniform row skip
                    float fv = __shfl(f[r], split * CCH + i);
                    acc[r].x = fmaf(fv, w.x, acc[r].x);
                    acc[r].y = fmaf(fv, w.y, acc[r].y);
                    acc[r].z = fmaf(fv, w.z, acc[r].z);
                    acc[r].w = fmaf(fv, w.w, acc[r].w);
                }
            }
        }
        // cross-split reduction + store + BN stats
#pragma unroll
        for (int r = 0; r < RB; ++r) {
            if (r >= nr) break;
            float ax = acc[r].x, ay = acc[r].y, az = acc[r].z, aw = acc[r].w;
#pragma unroll
            for (int off = DQ; off < 64; off <<= 1) {
                ax += __shfl_xor(ax, off);
                ay += __shfl_xor(ay, off);
                az += __shfl_xor(az, off);
                aw += __shfl_xor(aw, off);
            }
            if (split == 0) {
                TOUT* ob = out + (size_t)(row0 + r) * COUT + d4 * 4;
                stf(ob + 0, ax); stf(ob + 1, ay); stf(ob + 2, az); stf(ob + 3, aw);
                s0 += ax; s1 += ay; s2 += az; s3 += aw;
                q0 += ax * ax; q1 += ay * ay; q2 += az * az; q3 += aw * aw;
            }
        }
    }
    if (split == 0) {
        atomicAdd(&ssum[d4 * 4 + 0], s0);
        atomicAdd(&ssum[d4 * 4 + 1], s1);
        atomicAdd(&ssum[d4 * 4 + 2], s2);
        atomicAdd(&ssum[d4 * 4 + 3], s3);
        atomicAdd(&ssq[d4 * 4 + 0], q0);
        atomicAdd(&ssq[d4 * 4 + 1], q1);
        atomicAdd(&ssq[d4 * 4 + 2], q2);
        atomicAdd(&ssq[d4 * 4 + 3], q3);
    }
}

// ---------------- BN finalize: scale/shift from sums ----------------
__global__ void k_fin(const float* __restrict__ ssum, const float* __restrict__ ssq,
                      const float* __restrict__ g, const float* __restrict__ b,
                      float* __restrict__ scale, float* __restrict__ shift,
                      int C, float invN) {
    int c = blockIdx.x * blockDim.x + threadIdx.x;
    if (c >= C) return;
    float mu = ssum[c] * invN;
    float var = fmaxf(ssq[c] * invN - mu * mu, 0.f);
    float s = g[c] * rsqrtf(var + BN_EPS);
    scale[c] = s;
    shift[c] = b[c] - mu * s;
}

// ---- e0 = bnrelu(e0raw) in place (bf16); down[parent] += e0 @ W_down[off] (fp32 atomics) ----
__global__ __launch_bounds__(256) void k_down(__hip_bfloat16* __restrict__ e0,
                                              const int* __restrict__ parent,
                                              const int* __restrict__ child,
                                              const float* __restrict__ Wd,
                                              const float* __restrict__ sc,
                                              const float* __restrict__ sh,
                                              float* __restrict__ down, int N) {
    const int lane = threadIdx.x & 63;
    int wid = blockIdx.x * 4 + (threadIdx.x >> 6);
    int nw = gridDim.x * 4;
    for (int row = wid; row < N; row += nw) {
        int urow = rfl(row);
        float v = 0.f;
        if (lane < 32) {
            float r = ldf(e0 + (size_t)urow * 32 + lane);
            v = fmaxf(fmaf(r, sc[lane], sh[lane]), 0.f);
            stf(e0 + (size_t)urow * 32 + lane, v);  // post-BN e0, consumed by dec
        }
        int par = rfl(parent[urow]);
        int off = rfl(child[urow]);
        float acc = 0.f;
        const float* wb = Wd + (size_t)off * 2048 + lane;  // W_down[off][c][lane]
#pragma unroll
        for (int c = 0; c < 32; ++c)
            acc = fmaf(__shfl(v, c), wb[c * 64], acc);
        atomicAdd(&down[(size_t)par * 64 + lane], acc);
    }
}

// ---- up[n] = bnrelu(e1raw)[parent[n]] @ W_up[off[n]] -> bf16 ----
__global__ __launch_bounds__(256) void k_up(const __hip_bfloat16* __restrict__ e1raw,
                                            const int* __restrict__ parent,
                                            const int* __restrict__ child,
                                            const float* __restrict__ Wu,
                                            const float* __restrict__ sc,
                                            const float* __restrict__ sh,
                                            __hip_bfloat16* __restrict__ up, int N) {
    const int lane = threadIdx.x & 63;
    int wid = blockIdx.x * 4 + (threadIdx.x >> 6);
    int nw = gridDim.x * 4;
    for (int row = wid; row < N; row += nw) {
        int urow = rfl(row);
        int par = rfl(parent[urow]);
        int off = rfl(child[urow]);
        float e = ldf(e1raw + (size_t)par * 64 + lane);
        float v = fmaxf(fmaf(e, sc[lane], sh[lane]), 0.f);  // BN on the fly
        int d = lane & 31, hi = lane >> 5;
        float acc = 0.f;
        const float* wb = Wu + (size_t)off * 2048 + (size_t)hi * 1024 + d;
#pragma unroll
        for (int c = 0; c < 32; ++c)
            acc = fmaf(__shfl(v, hi * 32 + c), wb[c * 32], acc);
        acc += __shfl_xor(acc, 32);
        if (hi == 0) stf(up + (size_t)urow * 32 + d, acc);
    }
}

// ---- feature = bnrelu(decraw); y = feature @ W_lin + b_lin ----
__global__ __launch_bounds__(256) void k_out(const __hip_bfloat16* __restrict__ dec,
                                             const float* __restrict__ sc,
                                             const float* __restrict__ sh,
                                             const float* __restrict__ Wl,
                                             const float* __restrict__ bl,
                                             float* __restrict__ y,
                                             float* __restrict__ feat, int N) {
    int n = blockIdx.x * 256 + threadIdx.x;
    if (n >= N) return;
    float f[32];
    const __hip_bfloat162* p = (const __hip_bfloat162*)(dec + (size_t)n * 32);
#pragma unroll
    for (int j = 0; j < 16; ++j) {
        float2 t = __bfloat1622float2(p[j]);
        f[2 * j + 0] = fmaxf(fmaf(t.x, sc[2 * j + 0], sh[2 * j + 0]), 0.f);
        f[2 * j + 1] = fmaxf(fmaf(t.y, sc[2 * j + 1], sh[2 * j + 1]), 0.f);
    }
    float4* fo = (float4*)(feat + (size_t)n * 32);
#pragma unroll
    for (int j = 0; j < 8; ++j)
        fo[j] = make_float4(f[4 * j], f[4 * j + 1], f[4 * j + 2], f[4 * j + 3]);
    float acc[20];
#pragma unroll
    for (int q = 0; q < 20; ++q) acc[q] = bl[q];
#pragma unroll
    for (int c = 0; c < 32; ++c) {
        float fc = f[c];
#pragma unroll
        for (int q = 0; q < 20; ++q) acc[q] = fmaf(fc, Wl[c * 20 + q], acc[q]);
    }
    float4* yo = (float4*)(y + (size_t)n * 20);
#pragma unroll
    for (int j = 0; j < 5; ++j)
        yo[j] = make_float4(acc[4 * j], acc[4 * j + 1], acc[4 * j + 2], acc[4 * j + 3]);
}

extern "C" void kernel_launch(void* const* d_in, const int* in_sizes, int n_in,
                              void* d_out, int out_size, void* d_ws, size_t ws_size,
                              hipStream_t stream) {
    const float* feats = (const float*)d_in[0];
    const int* nbr_f   = (const int*)d_in[1];
    const int* nbr_c   = (const int*)d_in[2];
    const int* parent  = (const int*)d_in[3];
    const int* child   = (const int*)d_in[4];
    const float* W_sub = (const float*)d_in[5];
    const float* W_e0  = (const float*)d_in[6];
    const float* g0    = (const float*)d_in[7];
    const float* b0    = (const float*)d_in[8];
    const float* W_dn  = (const float*)d_in[9];
    const float* W_e1  = (const float*)d_in[10];
    const float* g1    = (const float*)d_in[11];
    const float* b1    = (const float*)d_in[12];
    const float* W_up  = (const float*)d_in[13];
    const float* W_dec = (const float*)d_in[14];
    const float* g_o   = (const float*)d_in[15];
    const float* b_o   = (const float*)d_in[16];
    const float* W_lin = (const float*)d_in[17];
    const float* b_lin = (const float*)d_in[18];

    const int N = in_sizes[0] / 3;
    const int M = in_sizes[2] / 27;

    // --- workspace (~94.3 MB): overlapped live ranges ---
    // [0 .. R): xv fp32 (N*32, steps 1-2)  /  down fp32 (M*64, steps 4-5)
    //           up bf16 at [0..N*16) + decraw bf16 at [N*16..N*32) (steps 7-10)
    // [R .. R+512): BN stats
    float* wsf = (float*)d_ws;
    size_t R = (size_t)M * 64;
    if ((size_t)N * 32 > R) R = (size_t)N * 32;
    float* xv   = wsf;
    float* down = wsf;
    __hip_bfloat16* up     = (__hip_bfloat16*)wsf;
    __hip_bfloat16* decraw = (__hip_bfloat16*)(wsf + (size_t)N * 16);
    float* stats = wsf + R;
    // stats map: 0 sum0[32] | 32 sq0[32] | 64 sum1[64] | 128 sq1[64] |
    //            192 sumo[32] | 224 sqo[32] | 256 scale0 | 288 shift0 |
    //            320 scale1[64] | 384 shift1[64] | 448 scaleo | 480 shifto

    // --- d_out doubles as scratch: e0 bf16 [0..N*16 floats), e1raw bf16
    // [N*16..N*16+M*32); both dead before k_out writes y/feat (M <= N). ---
    __hip_bfloat16* e0    = (__hip_bfloat16*)d_out;
    __hip_bfloat16* e1raw = (__hip_bfloat16*)((float*)d_out + (size_t)N * 16);
    float* y    = (float*)d_out;
    float* feat = y + (size_t)N * 20;

    const int nblk = (N + 255) / 256;
    const int G = 2048;

    hipMemsetAsync(stats, 0, 256 * sizeof(float), stream);

    k_xv<<<nblk, 256, 0, stream>>>(feats, nbr_f, W_sub, xv, N);
    k_subconv<32, 32, 8, false, float, __hip_bfloat16>
        <<<G, 256, 0, stream>>>(xv, nullptr, nbr_f, W_e0, e0, N,
                                stats + 0, stats + 32);
    // xv dead; zero `down` (same region) for the atomic segment-sum
    hipMemsetAsync(down, 0, (size_t)M * 64 * sizeof(float), stream);
    k_fin<<<1, 64, 0, stream>>>(stats + 0, stats + 32, g0, b0,
                                stats + 256, stats + 288, 32, 1.f / (float)N);
    k_down<<<G, 256, 0, stream>>>(e0, parent, child, W_dn,
                                  stats + 256, stats + 288, down, N);
    k_subconv<64, 64, 8, false, float, __hip_bfloat16>
        <<<G, 256, 0, stream>>>(down, nullptr, nbr_c, W_e1, e1raw, M,
                                stats + 64, stats + 128);
    k_fin<<<1, 64, 0, stream>>>(stats + 64, stats + 128, g1, b1,
                                stats + 320, stats + 384, 64, 1.f / (float)M);
    k_up<<<G, 256, 0, stream>>>(e1raw, parent, child, W_up,
                                stats + 320, stats + 384, up, N);
    k_subconv<64, 32, 8, true, __hip_bfloat16, __hip_bfloat16>
        <<<G, 256, 0, stream>>>(e0, up, nbr_f, W_dec, decraw, N,
                                stats + 192, stats + 224);
    k_fin<<<1, 64, 0, stream>>>(stats + 192, stats + 224, g_o, b_o,
                                stats + 448, stats + 480, 32, 1.f / (float)N);
    k_out<<<nblk, 256, 0, stream>>>(decraw, stats + 448, stats + 480, W_lin, b_lin,
                                    y, feat, N);
}

// Round 6
// 3683.078 us; speedup vs baseline: 1.2767x; 1.1097x over previous
//
#include <hip/hip_runtime.h>
#include <hip/hip_bf16.h>

#define BN_EPS 1e-4f

__device__ __forceinline__ int rfl(int x) { return __builtin_amdgcn_readfirstlane(x); }

__device__ __forceinline__ float ldf(const float* p) { return *p; }
__device__ __forceinline__ float ldf(const __hip_bfloat16* p) { return __bfloat162float(*p); }
__device__ __forceinline__ void stf(float* p, float v) { *p = v; }
__device__ __forceinline__ void stf(__hip_bfloat16* p, float v) { *p = __float2bfloat16(v); }

// ---------------- xv = subconv(feats[N,3], nbr_fine, W_sub[27,3,32]) ----------------
__global__ __launch_bounds__(256) void k_xv(const float* __restrict__ feats,
                                            const int* __restrict__ nbr,
                                            const float* __restrict__ W,
                                            float* __restrict__ out, int N) {
    int n = blockIdx.x * 256 + threadIdx.x;
    if (n >= N) return;
    float acc[32];
#pragma unroll
    for (int d = 0; d < 32; ++d) acc[d] = 0.f;
    const int* nb = nbr + (size_t)n * 27;
    for (int k = 0; k < 27; ++k) {
        int idx = nb[k];
        if (idx < 0) continue;
        float f0 = feats[(size_t)idx * 3 + 0];
        float f1 = feats[(size_t)idx * 3 + 1];
        float f2 = feats[(size_t)idx * 3 + 2];
        const float* w = W + k * 96;  // k uniform -> scalar loads
#pragma unroll
        for (int d = 0; d < 32; ++d)
            acc[d] += f0 * w[d] + f1 * w[32 + d] + f2 * w[64 + d];
    }
    float4* o = (float4*)(out + (size_t)n * 32);
#pragma unroll
    for (int j = 0; j < 8; ++j)
        o[j] = make_float4(acc[4 * j], acc[4 * j + 1], acc[4 * j + 2], acc[4 * j + 3]);
}

// ------------- tap-pipelined row-blocked streaming-weight submanifold conv -------------
// RB=8 rows/wave. Tap k+1's nbr idx + 8 gathers prefetch into a second register
// set while tap k computes (load->use distance = one tap-compute; hides L3
// gather latency). Validity mask is readfirstlane'd to 8 scalar bits ->
// s_cbranch, no exec churn (R5 lesson). Inner loop: c4-chunk outer holds 4
// float4 weights in regs, row inner (branch sites 4x fewer than R5).
// Registers ~90; launch_bounds(256,4) caps at 128 -> no spill (R3/R4 lesson).
template <int CIN, int COUT, bool SPLIT, typename TIN, typename TOUT>
__global__ __launch_bounds__(256, 4) void k_subconv(const TIN* __restrict__ inA,
                                                    const TIN* __restrict__ inB,
                                                    const int* __restrict__ nbr,
                                                    const float* __restrict__ W,
                                                    TOUT* __restrict__ out, int nrows,
                                                    float* __restrict__ ssum,
                                                    float* __restrict__ ssq) {
    constexpr int RB = 8;             // rows per wave
    constexpr int DQ = COUT / 4;      // float4 output groups
    constexpr int NSPLIT = 64 / DQ;   // c-chunks
    constexpr int CCH = CIN / NSPLIT; // c per chunk (4, 8, or 16)
    const int lane = threadIdx.x & 63;
    const int split = lane / DQ;
    const int d4 = lane % DQ;
    int wid = blockIdx.x * 4 + (threadIdx.x >> 6);
    int nw = gridDim.x * 4;
    const int nblkrows = (nrows + RB - 1) / RB;
    float s0 = 0.f, s1 = 0.f, s2 = 0.f, s3 = 0.f;
    float q0 = 0.f, q1 = 0.f, q2 = 0.f, q3 = 0.f;
    for (int blk = wid; blk < nblkrows; blk += nw) {
        const int row0 = rfl(blk) * RB;
        int nr = nrows - row0;
        nr = nr > RB ? RB : nr;
        float4 acc[RB];
#pragma unroll
        for (int r = 0; r < RB; ++r) acc[r] = make_float4(0.f, 0.f, 0.f, 0.f);

        // ---- gather one tap's neighbor rows into registers (mask in scalar) ----
        auto load_tap = [&](int k, float f[RB]) -> int {
            int idx = (lane < nr) ? nbr[(size_t)(row0 + lane) * 27 + k] : -1;
            int m8 = rfl((int)(__ballot(idx >= 0) & 0xff));
#pragma unroll
            for (int r = 0; r < RB; ++r) {
                f[r] = 0.f;
                if (m8 & (1 << r)) {  // scalar branch
                    int ir = __shfl(idx, r);
                    if (SPLIT)
                        f[r] = (lane < 32) ? ldf(inA + (size_t)ir * 32 + lane)
                                           : ldf(inB + (size_t)ir * 32 + lane - 32);
                    else
                        f[r] = (CIN == 64 || lane < CIN)
                                   ? ldf(inA + (size_t)ir * CIN + lane) : 0.f;
                }
            }
            return m8;
        };

        float f[RB], f2[RB];
        int m = load_tap(0, f);
        for (int k = 0; k < 27; ++k) {
            int m2 = 0;
            if (k + 1 < 27) m2 = load_tap(k + 1, f2);  // prefetch next tap
            if (m) {
                // c4-chunk outer: 4 float4 weights live, reused across rows
#pragma unroll
                for (int c = 0; c < CCH / 4; ++c) {
                    const float4* ws =
                        (const float4*)(W + ((size_t)k * CIN + split * CCH + c * 4) * COUT) + d4;
                    float4 w0 = ws[0 * DQ], w1 = ws[1 * DQ];
                    float4 w2 = ws[2 * DQ], w3 = ws[3 * DQ];
#pragma unroll
                    for (int r = 0; r < RB; ++r) {
                        if (!(m & (1 << r))) continue;  // scalar row skip
                        float v0 = __shfl(f[r], split * CCH + c * 4 + 0);
                        float v1 = __shfl(f[r], split * CCH + c * 4 + 1);
                        float v2 = __shfl(f[r], split * CCH + c * 4 + 2);
                        float v3 = __shfl(f[r], split * CCH + c * 4 + 3);
                        acc[r].x = fmaf(v0, w0.x, acc[r].x);
                        acc[r].y = fmaf(v0, w0.y, acc[r].y);
                        acc[r].z = fmaf(v0, w0.z, acc[r].z);
                        acc[r].w = fmaf(v0, w0.w, acc[r].w);
                        acc[r].x = fmaf(v1, w1.x, acc[r].x);
                        acc[r].y = fmaf(v1, w1.y, acc[r].y);
                        acc[r].z = fmaf(v1, w1.z, acc[r].z);
                        acc[r].w = fmaf(v1, w1.w, acc[r].w);
                        acc[r].x = fmaf(v2, w2.x, acc[r].x);
                        acc[r].y = fmaf(v2, w2.y, acc[r].y);
                        acc[r].z = fmaf(v2, w2.z, acc[r].z);
                        acc[r].w = fmaf(v2, w2.w, acc[r].w);
                        acc[r].x = fmaf(v3, w3.x, acc[r].x);
                        acc[r].y = fmaf(v3, w3.y, acc[r].y);
                        acc[r].z = fmaf(v3, w3.z, acc[r].z);
                        acc[r].w = fmaf(v3, w3.w, acc[r].w);
                    }
                }
            }
            m = m2;
#pragma unroll
            for (int r = 0; r < RB; ++r) f[r] = f2[r];
        }
        // cross-split reduction + store + BN stats
#pragma unroll
        for (int r = 0; r < RB; ++r) {
            if (r >= nr) break;
            float ax = acc[r].x, ay = acc[r].y, az = acc[r].z, aw = acc[r].w;
#pragma unroll
            for (int off = DQ; off < 64; off <<= 1) {
                ax += __shfl_xor(ax, off);
                ay += __shfl_xor(ay, off);
                az += __shfl_xor(az, off);
                aw += __shfl_xor(aw, off);
            }
            if (split == 0) {
                TOUT* ob = out + (size_t)(row0 + r) * COUT + d4 * 4;
                stf(ob + 0, ax); stf(ob + 1, ay); stf(ob + 2, az); stf(ob + 3, aw);
                s0 += ax; s1 += ay; s2 += az; s3 += aw;
                q0 += ax * ax; q1 += ay * ay; q2 += az * az; q3 += aw * aw;
            }
        }
    }
    if (split == 0) {
        atomicAdd(&ssum[d4 * 4 + 0], s0);
        atomicAdd(&ssum[d4 * 4 + 1], s1);
        atomicAdd(&ssum[d4 * 4 + 2], s2);
        atomicAdd(&ssum[d4 * 4 + 3], s3);
        atomicAdd(&ssq[d4 * 4 + 0], q0);
        atomicAdd(&ssq[d4 * 4 + 1], q1);
        atomicAdd(&ssq[d4 * 4 + 2], q2);
        atomicAdd(&ssq[d4 * 4 + 3], q3);
    }
}

// ---------------- BN finalize: scale/shift from sums ----------------
__global__ void k_fin(const float* __restrict__ ssum, const float* __restrict__ ssq,
                      const float* __restrict__ g, const float* __restrict__ b,
                      float* __restrict__ scale, float* __restrict__ shift,
                      int C, float invN) {
    int c = blockIdx.x * blockDim.x + threadIdx.x;
    if (c >= C) return;
    float mu = ssum[c] * invN;
    float var = fmaxf(ssq[c] * invN - mu * mu, 0.f);
    float s = g[c] * rsqrtf(var + BN_EPS);
    scale[c] = s;
    shift[c] = b[c] - mu * s;
}

// ---- e0 = bnrelu(e0raw) in place (bf16); down[parent] += e0 @ W_down[off] (fp32 atomics) ----
__global__ __launch_bounds__(256) void k_down(__hip_bfloat16* __restrict__ e0,
                                              const int* __restrict__ parent,
                                              const int* __restrict__ child,
                                              const float* __restrict__ Wd,
                                              const float* __restrict__ sc,
                                              const float* __restrict__ sh,
                                              float* __restrict__ down, int N) {
    const int lane = threadIdx.x & 63;
    int wid = blockIdx.x * 4 + (threadIdx.x >> 6);
    int nw = gridDim.x * 4;
    for (int row = wid; row < N; row += nw) {
        int urow = rfl(row);
        float v = 0.f;
        if (lane < 32) {
            float r = ldf(e0 + (size_t)urow * 32 + lane);
            v = fmaxf(fmaf(r, sc[lane], sh[lane]), 0.f);
            stf(e0 + (size_t)urow * 32 + lane, v);  // post-BN e0, consumed by dec
        }
        int par = rfl(parent[urow]);
        int off = rfl(child[urow]);
        float acc = 0.f;
        const float* wb = Wd + (size_t)off * 2048 + lane;  // W_down[off][c][lane]
#pragma unroll
        for (int c = 0; c < 32; ++c)
            acc = fmaf(__shfl(v, c), wb[c * 64], acc);
        atomicAdd(&down[(size_t)par * 64 + lane], acc);
    }
}

// ---- up[n] = bnrelu(e1raw)[parent[n]] @ W_up[off[n]] -> bf16 ----
__global__ __launch_bounds__(256) void k_up(const __hip_bfloat16* __restrict__ e1raw,
                                            const int* __restrict__ parent,
                                            const int* __restrict__ child,
                                            const float* __restrict__ Wu,
                                            const float* __restrict__ sc,
                                            const float* __restrict__ sh,
                                            __hip_bfloat16* __restrict__ up, int N) {
    const int lane = threadIdx.x & 63;
    int wid = blockIdx.x * 4 + (threadIdx.x >> 6);
    int nw = gridDim.x * 4;
    for (int row = wid; row < N; row += nw) {
        int urow = rfl(row);
        int par = rfl(parent[urow]);
        int off = rfl(child[urow]);
        float e = ldf(e1raw + (size_t)par * 64 + lane);
        float v = fmaxf(fmaf(e, sc[lane], sh[lane]), 0.f);  // BN on the fly
        int d = lane & 31, hi = lane >> 5;
        float acc = 0.f;
        const float* wb = Wu + (size_t)off * 2048 + (size_t)hi * 1024 + d;
#pragma unroll
        for (int c = 0; c < 32; ++c)
            acc = fmaf(__shfl(v, hi * 32 + c), wb[c * 32], acc);
        acc += __shfl_xor(acc, 32);
        if (hi == 0) stf(up + (size_t)urow * 32 + d, acc);
    }
}

// ---- feature = bnrelu(decraw); y = feature @ W_lin + b_lin ----
__global__ __launch_bounds__(256) void k_out(const __hip_bfloat16* __restrict__ dec,
                                             const float* __restrict__ sc,
                                             const float* __restrict__ sh,
                                             const float* __restrict__ Wl,
                                             const float* __restrict__ bl,
                                             float* __restrict__ y,
                                             float* __restrict__ feat, int N) {
    int n = blockIdx.x * 256 + threadIdx.x;
    if (n >= N) return;
    float f[32];
    const __hip_bfloat162* p = (const __hip_bfloat162*)(dec + (size_t)n * 32);
#pragma unroll
    for (int j = 0; j < 16; ++j) {
        float2 t = __bfloat1622float2(p[j]);
        f[2 * j + 0] = fmaxf(fmaf(t.x, sc[2 * j + 0], sh[2 * j + 0]), 0.f);
        f[2 * j + 1] = fmaxf(fmaf(t.y, sc[2 * j + 1], sh[2 * j + 1]), 0.f);
    }
    float4* fo = (float4*)(feat + (size_t)n * 32);
#pragma unroll
    for (int j = 0; j < 8; ++j)
        fo[j] = make_float4(f[4 * j], f[4 * j + 1], f[4 * j + 2], f[4 * j + 3]);
    float acc[20];
#pragma unroll
    for (int q = 0; q < 20; ++q) acc[q] = bl[q];
#pragma unroll
    for (int c = 0; c < 32; ++c) {
        float fc = f[c];
#pragma unroll
        for (int q = 0; q < 20; ++q) acc[q] = fmaf(fc, Wl[c * 20 + q], acc[q]);
    }
    float4* yo = (float4*)(y + (size_t)n * 20);
#pragma unroll
    for (int j = 0; j < 5; ++j)
        yo[j] = make_float4(acc[4 * j], acc[4 * j + 1], acc[4 * j + 2], acc[4 * j + 3]);
}

extern "C" void kernel_launch(void* const* d_in, const int* in_sizes, int n_in,
                              void* d_out, int out_size, void* d_ws, size_t ws_size,
                              hipStream_t stream) {
    const float* feats = (const float*)d_in[0];
    const int* nbr_f   = (const int*)d_in[1];
    const int* nbr_c   = (const int*)d_in[2];
    const int* parent  = (const int*)d_in[3];
    const int* child   = (const int*)d_in[4];
    const float* W_sub = (const float*)d_in[5];
    const float* W_e0  = (const float*)d_in[6];
    const float* g0    = (const float*)d_in[7];
    const float* b0    = (const float*)d_in[8];
    const float* W_dn  = (const float*)d_in[9];
    const float* W_e1  = (const float*)d_in[10];
    const float* g1    = (const float*)d_in[11];
    const float* b1    = (const float*)d_in[12];
    const float* W_up  = (const float*)d_in[13];
    const float* W_dec = (const float*)d_in[14];
    const float* g_o   = (const float*)d_in[15];
    const float* b_o   = (const float*)d_in[16];
    const float* W_lin = (const float*)d_in[17];
    const float* b_lin = (const float*)d_in[18];

    const int N = in_sizes[0] / 3;
    const int M = in_sizes[2] / 27;

    // --- workspace (~94.3 MB): overlapped live ranges ---
    // [0 .. R): xv fp32 (N*32, steps 1-2)  /  down fp32 (M*64, steps 4-5)
    //           up bf16 at [0..N*16) + decraw bf16 at [N*16..N*32) (steps 7-10)
    // [R .. R+512): BN stats
    float* wsf = (float*)d_ws;
    size_t R = (size_t)M * 64;
    if ((size_t)N * 32 > R) R = (size_t)N * 32;
    float* xv   = wsf;
    float* down = wsf;
    __hip_bfloat16* up     = (__hip_bfloat16*)wsf;
    __hip_bfloat16* decraw = (__hip_bfloat16*)(wsf + (size_t)N * 16);
    float* stats = wsf + R;
    // stats map: 0 sum0[32] | 32 sq0[32] | 64 sum1[64] | 128 sq1[64] |
    //            192 sumo[32] | 224 sqo[32] | 256 scale0 | 288 shift0 |
    //            320 scale1[64] | 384 shift1[64] | 448 scaleo | 480 shifto

    // --- d_out doubles as scratch: e0 bf16 [0..N*16 floats), e1raw bf16
    // [N*16..N*16+M*32); both dead before k_out writes y/feat (M <= N). ---
    __hip_bfloat16* e0    = (__hip_bfloat16*)d_out;
    __hip_bfloat16* e1raw = (__hip_bfloat16*)((float*)d_out + (size_t)N * 16);
    float* y    = (float*)d_out;
    float* feat = y + (size_t)N * 20;

    const int nblk = (N + 255) / 256;
    const int G = 2048;

    hipMemsetAsync(stats, 0, 256 * sizeof(float), stream);

    k_xv<<<nblk, 256, 0, stream>>>(feats, nbr_f, W_sub, xv, N);
    k_subconv<32, 32, false, float, __hip_bfloat16>
        <<<G, 256, 0, stream>>>(xv, nullptr, nbr_f, W_e0, e0, N,
                                stats + 0, stats + 32);
    // xv dead; zero `down` (same region) for the atomic segment-sum
    hipMemsetAsync(down, 0, (size_t)M * 64 * sizeof(float), stream);
    k_fin<<<1, 64, 0, stream>>>(stats + 0, stats + 32, g0, b0,
                                stats + 256, stats + 288, 32, 1.f / (float)N);
    k_down<<<G, 256, 0, stream>>>(e0, parent, child, W_dn,
                                  stats + 256, stats + 288, down, N);
    k_subconv<64, 64, false, float, __hip_bfloat16>
        <<<G, 256, 0, stream>>>(down, nullptr, nbr_c, W_e1, e1raw, M,
                                stats + 64, stats + 128);
    k_fin<<<1, 64, 0, stream>>>(stats + 64, stats + 128, g1, b1,
                                stats + 320, stats + 384, 64, 1.f / (float)M);
    k_up<<<G, 256, 0, stream>>>(e1raw, parent, child, W_up,
                                stats + 320, stats + 384, up, N);
    k_subconv<64, 32, true, __hip_bfloat16, __hip_bfloat16>
        <<<G, 256, 0, stream>>>(e0, up, nbr_f, W_dec, decraw, N,
                                stats + 192, stats + 224);
    k_fin<<<1, 64, 0, stream>>>(stats + 192, stats + 224, g_o, b_o,
                                stats + 448, stats + 480, 32, 1.f / (float)N);
    k_out<<<nblk, 256, 0, stream>>>(decraw, stats + 448, stats + 480, W_lin, b_lin,
                                    y, feat, N);
}

// Round 7
// 3633.884 us; speedup vs baseline: 1.2940x; 1.0135x over previous
//
#include <hip/hip_runtime.h>
#include <hip/hip_bf16.h>

#define BN_EPS 1e-4f

__device__ __forceinline__ int rfl(int x) { return __builtin_amdgcn_readfirstlane(x); }

__device__ __forceinline__ float ldf(const float* p) { return *p; }
__device__ __forceinline__ float ldf(const __hip_bfloat16* p) { return __bfloat162float(*p); }
__device__ __forceinline__ void stf(float* p, float v) { *p = v; }
__device__ __forceinline__ void stf(__hip_bfloat16* p, float v) { *p = __float2bfloat16(v); }

// weight float4 loader: fp32 direct, bf16 via 2x bfloat162 convert
__device__ __forceinline__ float4 ldw4(const float* p) { return *(const float4*)p; }
__device__ __forceinline__ float4 ldw4(const __hip_bfloat16* p) {
    const __hip_bfloat162* q = (const __hip_bfloat162*)p;
    float2 a = __bfloat1622float2(q[0]);
    float2 b = __bfloat1622float2(q[1]);
    return make_float4(a.x, a.y, b.x, b.y);
}

// ---------------- fp32 -> bf16 weight conversion ----------------
__global__ __launch_bounds__(256) void k_cvt(const float* __restrict__ src,
                                             __hip_bfloat16* __restrict__ dst, int n) {
    int i = blockIdx.x * 256 + threadIdx.x;
    if (i < n) dst[i] = __float2bfloat16(src[i]);
}

// ---------------- xv = subconv(feats[N,3], nbr_fine, W_sub[27,3,32]) ----------------
__global__ __launch_bounds__(256) void k_xv(const float* __restrict__ feats,
                                            const int* __restrict__ nbr,
                                            const float* __restrict__ W,
                                            float* __restrict__ out, int N) {
    int n = blockIdx.x * 256 + threadIdx.x;
    if (n >= N) return;
    float acc[32];
#pragma unroll
    for (int d = 0; d < 32; ++d) acc[d] = 0.f;
    const int* nb = nbr + (size_t)n * 27;
    for (int k = 0; k < 27; ++k) {
        int idx = nb[k];
        if (idx < 0) continue;
        float f0 = feats[(size_t)idx * 3 + 0];
        float f1 = feats[(size_t)idx * 3 + 1];
        float f2 = feats[(size_t)idx * 3 + 2];
        const float* w = W + k * 96;  // k uniform -> scalar loads
#pragma unroll
        for (int d = 0; d < 32; ++d)
            acc[d] += f0 * w[d] + f1 * w[32 + d] + f2 * w[64 + d];
    }
    float4* o = (float4*)(out + (size_t)n * 32);
#pragma unroll
    for (int j = 0; j < 8; ++j)
        o[j] = make_float4(acc[4 * j], acc[4 * j + 1], acc[4 * j + 2], acc[4 * j + 3]);
}

// ------------- LDS-idx-staged, tap-pipelined, row-blocked submanifold conv -------------
// RB=8 rows/wave. Per block: the 216 contiguous nbr ints are staged into a
// per-wave LDS region ONCE (tap-major, -1 padded) -> one global idx latency per
// block instead of 27 (R6 diagnosis). Per tap: 2 broadcast ds_read_b128 give
// all 8 indices to every lane (no shfl, no ballot); reads run two taps ahead
// so LDS latency is off the critical path. Gathers for tap k+1 issue during
// tap k's compute. Validity masks are lane-uniform -> readfirstlane -> scalar
// branches (R5 lesson). Weight chunks: 4 rows of float4 live at a time (no
// spill; R3/R4 lesson); TW=bf16 halves the per-tap weight L1 traffic for e1.
template <int CIN, int COUT, bool SPLIT, typename TW, typename TIN, typename TOUT>
__global__ __launch_bounds__(256, 4) void k_subconv(const TIN* __restrict__ inA,
                                                    const TIN* __restrict__ inB,
                                                    const int* __restrict__ nbr,
                                                    const TW* __restrict__ W,
                                                    TOUT* __restrict__ out, int nrows,
                                                    float* __restrict__ ssum,
                                                    float* __restrict__ ssq) {
    constexpr int RB = 8;             // rows per wave
    constexpr int DQ = COUT / 4;      // float4 output groups
    constexpr int NSPLIT = 64 / DQ;   // c-chunks
    constexpr int CCH = CIN / NSPLIT; // c per chunk (4, 8, or 16)
    __shared__ int sidx[4][240];      // per-wave idx buffer: 29 taps x 8 rows (+pad)
    const int tid = threadIdx.x;
    const int lane = tid & 63;
    const int wv = tid >> 6;
    const int split = lane / DQ;
    const int d4 = lane % DQ;
    int* my = sidx[wv];
    int wid = blockIdx.x * 4 + wv;
    int nw = gridDim.x * 4;
    const int nblkrows = (nrows + RB - 1) / RB;
    float s0 = 0.f, s1 = 0.f, s2 = 0.f, s3 = 0.f;
    float q0 = 0.f, q1 = 0.f, q2 = 0.f, q3 = 0.f;

    auto read_idx = [&](int k, int ir[8]) {
        int4 a = *(const int4*)&my[k * 8];
        int4 b = *(const int4*)&my[k * 8 + 4];
        ir[0] = a.x; ir[1] = a.y; ir[2] = a.z; ir[3] = a.w;
        ir[4] = b.x; ir[5] = b.y; ir[6] = b.z; ir[7] = b.w;
    };
    auto mask8 = [&](const int ir[8]) {
        int m = 0;
#pragma unroll
        for (int r = 0; r < 8; ++r) m |= (ir[r] >= 0) ? (1 << r) : 0;
        return rfl(m);  // lane-uniform -> scalar
    };
    auto gather = [&](const int ir[8], int m8, float f[8]) {
#pragma unroll
        for (int r = 0; r < 8; ++r) {
            f[r] = 0.f;
            if (m8 & (1 << r)) {  // scalar branch
                int idx = ir[r];
                if (SPLIT)
                    f[r] = (lane < 32) ? ldf(inA + (size_t)idx * 32 + lane)
                                       : ldf(inB + (size_t)idx * 32 + lane - 32);
                else
                    f[r] = (CIN == 64 || lane < CIN)
                               ? ldf(inA + (size_t)idx * CIN + lane) : 0.f;
            }
        }
    };

    for (int blk = wid; blk < nblkrows; blk += nw) {
        const int row0 = rfl(blk) * RB;
        int nr = nrows - row0;
        nr = nr > RB ? RB : nr;
        // ---- stage this block's nbr rows into LDS (tap-major, -1 pad) ----
        for (int t = lane; t < 240; t += 64) my[t] = -1;
        const int* src = nbr + (size_t)row0 * 27;
        const int tot = nr * 27;
        for (int t = lane; t < tot; t += 64) {
            int v = src[t];  // fully coalesced
            my[(t % 27) * 8 + (t / 27)] = v;
        }
        // (same-wave ds_write -> ds_read ordering; compiler emits lgkmcnt)
        float4 acc[RB];
#pragma unroll
        for (int r = 0; r < RB; ++r) acc[r] = make_float4(0.f, 0.f, 0.f, 0.f);

        int ira[8], irb[8];
        read_idx(0, ira);
        read_idx(1, irb);
        int ma = mask8(ira);
        float f[RB];
        gather(ira, ma, f);
        for (int k = 0; k < 27; ++k) {
            int mb = mask8(irb);          // idx read 1-2 iters ago: latency gone
            float f2[RB];
            gather(irb, mb, f2);          // prefetch gathers for tap k+1
            read_idx(k + 2, irb);         // k+2 <= 28: pad rows are -1
            if (ma) {
#pragma unroll
                for (int c = 0; c < CCH / 4; ++c) {
                    const TW* wb = W + ((size_t)k * CIN + split * CCH + c * 4) * COUT + d4 * 4;
                    float4 w0 = ldw4(wb + 0 * COUT);
                    float4 w1 = ldw4(wb + 1 * COUT);
                    float4 w2 = ldw4(wb + 2 * COUT);
                    float4 w3 = ldw4(wb + 3 * COUT);
#pragma unroll
                    for (int r = 0; r < RB; ++r) {
                        if (!(ma & (1 << r))) continue;  // scalar row skip
                        float v0 = __shfl(f[r], split * CCH + c * 4 + 0);
                        float v1 = __shfl(f[r], split * CCH + c * 4 + 1);
                        float v2 = __shfl(f[r], split * CCH + c * 4 + 2);
                        float v3 = __shfl(f[r], split * CCH + c * 4 + 3);
                        acc[r].x = fmaf(v0, w0.x, acc[r].x);
                        acc[r].y = fmaf(v0, w0.y, acc[r].y);
                        acc[r].z = fmaf(v0, w0.z, acc[r].z);
                        acc[r].w = fmaf(v0, w0.w, acc[r].w);
                        acc[r].x = fmaf(v1, w1.x, acc[r].x);
                        acc[r].y = fmaf(v1, w1.y, acc[r].y);
                        acc[r].z = fmaf(v1, w1.z, acc[r].z);
                        acc[r].w = fmaf(v1, w1.w, acc[r].w);
                        acc[r].x = fmaf(v2, w2.x, acc[r].x);
                        acc[r].y = fmaf(v2, w2.y, acc[r].y);
                        acc[r].z = fmaf(v2, w2.z, acc[r].z);
                        acc[r].w = fmaf(v2, w2.w, acc[r].w);
                        acc[r].x = fmaf(v3, w3.x, acc[r].x);
                        acc[r].y = fmaf(v3, w3.y, acc[r].y);
                        acc[r].z = fmaf(v3, w3.z, acc[r].z);
                        acc[r].w = fmaf(v3, w3.w, acc[r].w);
                    }
                }
            }
            ma = mb;
#pragma unroll
            for (int r = 0; r < RB; ++r) f[r] = f2[r];
        }
        // ---- cross-split reduction + store + BN stats ----
#pragma unroll
        for (int r = 0; r < RB; ++r) {
            if (r >= nr) break;
            float ax = acc[r].x, ay = acc[r].y, az = acc[r].z, aw = acc[r].w;
#pragma unroll
            for (int off = DQ; off < 64; off <<= 1) {
                ax += __shfl_xor(ax, off);
                ay += __shfl_xor(ay, off);
                az += __shfl_xor(az, off);
                aw += __shfl_xor(aw, off);
            }
            if (split == 0) {
                TOUT* ob = out + (size_t)(row0 + r) * COUT + d4 * 4;
                stf(ob + 0, ax); stf(ob + 1, ay); stf(ob + 2, az); stf(ob + 3, aw);
                s0 += ax; s1 += ay; s2 += az; s3 += aw;
                q0 += ax * ax; q1 += ay * ay; q2 += az * az; q3 += aw * aw;
            }
        }
    }
    if (split == 0) {
        atomicAdd(&ssum[d4 * 4 + 0], s0);
        atomicAdd(&ssum[d4 * 4 + 1], s1);
        atomicAdd(&ssum[d4 * 4 + 2], s2);
        atomicAdd(&ssum[d4 * 4 + 3], s3);
        atomicAdd(&ssq[d4 * 4 + 0], q0);
        atomicAdd(&ssq[d4 * 4 + 1], q1);
        atomicAdd(&ssq[d4 * 4 + 2], q2);
        atomicAdd(&ssq[d4 * 4 + 3], q3);
    }
}

// ---------------- BN finalize: scale/shift from sums ----------------
__global__ void k_fin(const float* __restrict__ ssum, const float* __restrict__ ssq,
                      const float* __restrict__ g, const float* __restrict__ b,
                      float* __restrict__ scale, float* __restrict__ shift,
                      int C, float invN) {
    int c = blockIdx.x * blockDim.x + threadIdx.x;
    if (c >= C) return;
    float mu = ssum[c] * invN;
    float var = fmaxf(ssq[c] * invN - mu * mu, 0.f);
    float s = g[c] * rsqrtf(var + BN_EPS);
    scale[c] = s;
    shift[c] = b[c] - mu * s;
}

// ---- e0 = bnrelu(e0raw) in place (bf16); down[parent] += e0 @ W_down[off] (fp32 atomics) ----
__global__ __launch_bounds__(256) void k_down(__hip_bfloat16* __restrict__ e0,
                                              const int* __restrict__ parent,
                                              const int* __restrict__ child,
                                              const float* __restrict__ Wd,
                                              const float* __restrict__ sc,
                                              const float* __restrict__ sh,
                                              float* __restrict__ down, int N) {
    const int lane = threadIdx.x & 63;
    int wid = blockIdx.x * 4 + (threadIdx.x >> 6);
    int nw = gridDim.x * 4;
    for (int row = wid; row < N; row += nw) {
        int urow = rfl(row);
        float v = 0.f;
        if (lane < 32) {
            float r = ldf(e0 + (size_t)urow * 32 + lane);
            v = fmaxf(fmaf(r, sc[lane], sh[lane]), 0.f);
            stf(e0 + (size_t)urow * 32 + lane, v);  // post-BN e0, consumed by dec
        }
        int par = rfl(parent[urow]);
        int off = rfl(child[urow]);
        float acc = 0.f;
        const float* wb = Wd + (size_t)off * 2048 + lane;  // W_down[off][c][lane]
#pragma unroll
        for (int c = 0; c < 32; ++c)
            acc = fmaf(__shfl(v, c), wb[c * 64], acc);
        atomicAdd(&down[(size_t)par * 64 + lane], acc);
    }
}

// ---- up[n] = bnrelu(e1raw)[parent[n]] @ W_up[off[n]] -> bf16 ----
__global__ __launch_bounds__(256) void k_up(const __hip_bfloat16* __restrict__ e1raw,
                                            const int* __restrict__ parent,
                                            const int* __restrict__ child,
                                            const float* __restrict__ Wu,
                                            const float* __restrict__ sc,
                                            const float* __restrict__ sh,
                                            __hip_bfloat16* __restrict__ up, int N) {
    const int lane = threadIdx.x & 63;
    int wid = blockIdx.x * 4 + (threadIdx.x >> 6);
    int nw = gridDim.x * 4;
    for (int row = wid; row < N; row += nw) {
        int urow = rfl(row);
        int par = rfl(parent[urow]);
        int off = rfl(child[urow]);
        float e = ldf(e1raw + (size_t)par * 64 + lane);
        float v = fmaxf(fmaf(e, sc[lane], sh[lane]), 0.f);  // BN on the fly
        int d = lane & 31, hi = lane >> 5;
        float acc = 0.f;
        const float* wb = Wu + (size_t)off * 2048 + (size_t)hi * 1024 + d;
#pragma unroll
        for (int c = 0; c < 32; ++c)
            acc = fmaf(__shfl(v, hi * 32 + c), wb[c * 32], acc);
        acc += __shfl_xor(acc, 32);
        if (hi == 0) stf(up + (size_t)urow * 32 + d, acc);
    }
}

// ---- feature = bnrelu(decraw); y = feature @ W_lin + b_lin ----
__global__ __launch_bounds__(256) void k_out(const __hip_bfloat16* __restrict__ dec,
                                             const float* __restrict__ sc,
                                             const float* __restrict__ sh,
                                             const float* __restrict__ Wl,
                                             const float* __restrict__ bl,
                                             float* __restrict__ y,
                                             float* __restrict__ feat, int N) {
    int n = blockIdx.x * 256 + threadIdx.x;
    if (n >= N) return;
    float f[32];
    const __hip_bfloat162* p = (const __hip_bfloat162*)(dec + (size_t)n * 32);
#pragma unroll
    for (int j = 0; j < 16; ++j) {
        float2 t = __bfloat1622float2(p[j]);
        f[2 * j + 0] = fmaxf(fmaf(t.x, sc[2 * j + 0], sh[2 * j + 0]), 0.f);
        f[2 * j + 1] = fmaxf(fmaf(t.y, sc[2 * j + 1], sh[2 * j + 1]), 0.f);
    }
    float4* fo = (float4*)(feat + (size_t)n * 32);
#pragma unroll
    for (int j = 0; j < 8; ++j)
        fo[j] = make_float4(f[4 * j], f[4 * j + 1], f[4 * j + 2], f[4 * j + 3]);
    float acc[20];
#pragma unroll
    for (int q = 0; q < 20; ++q) acc[q] = bl[q];
#pragma unroll
    for (int c = 0; c < 32; ++c) {
        float fc = f[c];
#pragma unroll
        for (int q = 0; q < 20; ++q) acc[q] = fmaf(fc, Wl[c * 20 + q], acc[q]);
    }
    float4* yo = (float4*)(y + (size_t)n * 20);
#pragma unroll
    for (int j = 0; j < 5; ++j)
        yo[j] = make_float4(acc[4 * j], acc[4 * j + 1], acc[4 * j + 2], acc[4 * j + 3]);
}

extern "C" void kernel_launch(void* const* d_in, const int* in_sizes, int n_in,
                              void* d_out, int out_size, void* d_ws, size_t ws_size,
                              hipStream_t stream) {
    const float* feats = (const float*)d_in[0];
    const int* nbr_f   = (const int*)d_in[1];
    const int* nbr_c   = (const int*)d_in[2];
    const int* parent  = (const int*)d_in[3];
    const int* child   = (const int*)d_in[4];
    const float* W_sub = (const float*)d_in[5];
    const float* W_e0  = (const float*)d_in[6];
    const float* g0    = (const float*)d_in[7];
    const float* b0    = (const float*)d_in[8];
    const float* W_dn  = (const float*)d_in[9];
    const float* W_e1  = (const float*)d_in[10];
    const float* g1    = (const float*)d_in[11];
    const float* b1    = (const float*)d_in[12];
    const float* W_up  = (const float*)d_in[13];
    const float* W_dec = (const float*)d_in[14];
    const float* g_o   = (const float*)d_in[15];
    const float* b_o   = (const float*)d_in[16];
    const float* W_lin = (const float*)d_in[17];
    const float* b_lin = (const float*)d_in[18];

    const int N = in_sizes[0] / 3;
    const int M = in_sizes[2] / 27;
    const int NW_E1 = 27 * 64 * 64;  // W_e1 element count

    // --- workspace (~94.3 MB): overlapped live ranges ---
    // [0 .. R): xv fp32 (N*32, steps 1-2)  /  down fp32 (M*64, steps 4-5)
    //           up bf16 at [0..N*16) + decraw bf16 at [N*16..N*32) (steps 7-10)
    // [R .. R+512): BN stats
    float* wsf = (float*)d_ws;
    size_t R = (size_t)M * 64;
    if ((size_t)N * 32 > R) R = (size_t)N * 32;
    float* xv   = wsf;
    float* down = wsf;
    __hip_bfloat16* up     = (__hip_bfloat16*)wsf;
    __hip_bfloat16* decraw = (__hip_bfloat16*)(wsf + (size_t)N * 16);
    float* stats = wsf + R;
    // stats map: 0 sum0[32] | 32 sq0[32] | 64 sum1[64] | 128 sq1[64] |
    //            192 sumo[32] | 224 sqo[32] | 256 scale0 | 288 shift0 |
    //            320 scale1[64] | 384 shift1[64] | 448 scaleo | 480 shifto

    // --- d_out doubles as scratch: e0 bf16 [0..N*16 floats), e1raw bf16
    // [N*16..N*16+M*32), W_e1 bf16 copy right after (dead before k_out
    // rewrites y/feat; N*16+M*32+NW_E1/2 < N*52 since M <= N). ---
    __hip_bfloat16* e0    = (__hip_bfloat16*)d_out;
    __hip_bfloat16* e1raw = (__hip_bfloat16*)((float*)d_out + (size_t)N * 16);
    __hip_bfloat16* We1b  = (__hip_bfloat16*)((float*)d_out + (size_t)N * 16 + (size_t)M * 32);
    float* y    = (float*)d_out;
    float* feat = y + (size_t)N * 20;

    const int nblk = (N + 255) / 256;
    const int G = 2048;

    hipMemsetAsync(stats, 0, 256 * sizeof(float), stream);
    k_cvt<<<(NW_E1 + 255) / 256, 256, 0, stream>>>(W_e1, We1b, NW_E1);

    k_xv<<<nblk, 256, 0, stream>>>(feats, nbr_f, W_sub, xv, N);
    k_subconv<32, 32, false, float, float, __hip_bfloat16>
        <<<G, 256, 0, stream>>>(xv, nullptr, nbr_f, W_e0, e0, N,
                                stats + 0, stats + 32);
    // xv dead; zero `down` (same region) for the atomic segment-sum
    hipMemsetAsync(down, 0, (size_t)M * 64 * sizeof(float), stream);
    k_fin<<<1, 64, 0, stream>>>(stats + 0, stats + 32, g0, b0,
                                stats + 256, stats + 288, 32, 1.f / (float)N);
    k_down<<<G, 256, 0, stream>>>(e0, parent, child, W_dn,
                                  stats + 256, stats + 288, down, N);
    k_subconv<64, 64, false, __hip_bfloat16, float, __hip_bfloat16>
        <<<G, 256, 0, stream>>>(down, nullptr, nbr_c, We1b, e1raw, M,
                                stats + 64, stats + 128);
    k_fin<<<1, 64, 0, stream>>>(stats + 64, stats + 128, g1, b1,
                                stats + 320, stats + 384, 64, 1.f / (float)M);
    k_up<<<G, 256, 0, stream>>>(e1raw, parent, child, W_up,
                                stats + 320, stats + 384, up, N);
    k_subconv<64, 32, true, float, __hip_bfloat16, __hip_bfloat16>
        <<<G, 256, 0, stream>>>(e0, up, nbr_f, W_dec, decraw, N,
                                stats + 192, stats + 224);
    k_fin<<<1, 64, 0, stream>>>(stats + 192, stats + 224, g_o, b_o,
                                stats + 448, stats + 480, 32, 1.f / (float)N);
    k_out<<<nblk, 256, 0, stream>>>(decraw, stats + 448, stats + 480, W_lin, b_lin,
                                    y, feat, N);
}

// Round 8
// 1691.924 us; speedup vs baseline: 2.7793x; 2.1478x over previous
//
#include <hip/hip_runtime.h>
#include <hip/hip_bf16.h>

#define BN_EPS 1e-4f

typedef __attribute__((ext_vector_type(8))) short short8;   // 8 bf16 = 4 VGPR (MFMA A/B frag)
typedef __attribute__((ext_vector_type(4))) float float4e;  // MFMA C/D frag

__device__ __forceinline__ int rfl(int x) { return __builtin_amdgcn_readfirstlane(x); }

__device__ __forceinline__ float ldf(const __hip_bfloat16* p) { return __bfloat162float(*p); }
__device__ __forceinline__ void stf(__hip_bfloat16* p, float v) { *p = __float2bfloat16(v); }

__device__ __forceinline__ short bfbits(float x) {
    __hip_bfloat16 h = __float2bfloat16(x);
    short s;
    __builtin_memcpy(&s, &h, 2);
    return s;
}
__device__ __forceinline__ short8 cvt8(float4 a, float4 b) {
    short8 r;
    r[0] = bfbits(a.x); r[1] = bfbits(a.y); r[2] = bfbits(a.z); r[3] = bfbits(a.w);
    r[4] = bfbits(b.x); r[5] = bfbits(b.y); r[6] = bfbits(b.z); r[7] = bfbits(b.w);
    return r;
}

// ---- pack W fp32 [27][CIN][COUT] -> bf16 B-fragment table [27][KT][NT][lane][8] ----
// element j of lane = W[t][kt*32 + (lane>>4)*8 + j][nt*16 + (lane&15)]
__global__ __launch_bounds__(256) void k_pack(const float* __restrict__ src,
                                              __hip_bfloat16* __restrict__ dst,
                                              int CIN, int COUT, int KT, int NT, int total) {
    int i = blockIdx.x * 256 + threadIdx.x;
    if (i >= total) return;
    int j = i & 7, lane = (i >> 3) & 63;
    int g = i >> 9;
    int nt = g % NT; g /= NT;
    int kt = g % KT; g /= KT;
    int t = g;
    int q = lane >> 4, c = lane & 15;
    dst[i] = __float2bfloat16(src[((size_t)t * CIN + kt * 32 + q * 8 + j) * COUT + nt * 16 + c]);
}

// ---------------- xv = subconv(feats[N,3], nbr_fine, W_sub) -> bf16 ----------------
__global__ __launch_bounds__(256) void k_xv(const float* __restrict__ feats,
                                            const int* __restrict__ nbr,
                                            const float* __restrict__ W,
                                            __hip_bfloat16* __restrict__ out, int N) {
    int n = blockIdx.x * 256 + threadIdx.x;
    if (n >= N) return;
    float acc[32];
#pragma unroll
    for (int d = 0; d < 32; ++d) acc[d] = 0.f;
    const int* nb = nbr + (size_t)n * 27;
    for (int k = 0; k < 27; ++k) {
        int idx = nb[k];
        if (idx < 0) continue;
        float f0 = feats[(size_t)idx * 3 + 0];
        float f1 = feats[(size_t)idx * 3 + 1];
        float f2 = feats[(size_t)idx * 3 + 2];
        const float* w = W + k * 96;  // k uniform -> scalar loads
#pragma unroll
        for (int d = 0; d < 32; ++d)
            acc[d] += f0 * w[d] + f1 * w[32 + d] + f2 * w[64 + d];
    }
    short8* o = (short8*)(out + (size_t)n * 32);
#pragma unroll
    for (int c = 0; c < 4; ++c) {
        short8 r;
#pragma unroll
        for (int j = 0; j < 8; ++j) r[j] = bfbits(acc[c * 8 + j]);
        o[c] = r;
    }
}

// ---------------- MFMA submanifold conv ----------------
// Wave per 16-row tile. Per tap k: out[16,COUT] += A(gathered rows)[16,CIN] @ W[k].
// A-frag gathered DIRECTLY from global: lane reads 16B at in + idx[lane&15]*CIN
// + kt*32 + (lane>>4)*8  (A[m][k] layout m=lane&15, k=quad*8+j -> per-lane
// contiguous; no LDS transpose, no bank conflicts). Row idx per lane from an
// LDS tap-major table (broadcast reads), pipelined 2 taps ahead; gathers 1 tap
// ahead. B-frags from the pre-packed bf16 table (1 coalesced 16B load/lane,
// L2-resident). Invalid rows -> zero frags (branchless); tap skip scalar.
// MODE 0: bf16 single src (CIN=32) | 1: fp32 src + in-reg cvt (CIN=64)
// | 2: bf16 dual src e0|up (CIN=64).
template <int CIN, int COUT, int MODE>
__global__ __launch_bounds__(256, 4) void k_conv(const void* __restrict__ inAv,
                                                 const void* __restrict__ inBv,
                                                 const int* __restrict__ nbr,
                                                 const __hip_bfloat16* __restrict__ Wp,
                                                 __hip_bfloat16* __restrict__ out,
                                                 int nrows,
                                                 float* __restrict__ ssum,
                                                 float* __restrict__ ssq) {
    constexpr int KT = CIN / 32;   // MFMA k-tiles
    constexpr int NT = COUT / 16;  // MFMA n-tiles
    __shared__ int sidx[4][432];   // per-wave idx table [tap][row]
    const __hip_bfloat16* inAb = (const __hip_bfloat16*)inAv;
    const __hip_bfloat16* inBb = (const __hip_bfloat16*)inBv;
    const float* inAf = (const float*)inAv;
    const int tid = threadIdx.x;
    const int lane = tid & 63;
    const int wv = tid >> 6;
    const int m15 = lane & 15;
    const int q = lane >> 4;
    int* my = sidx[wv];
    int wid = blockIdx.x * 4 + wv;
    int nw = gridDim.x * 4;
    const int ntile = (nrows + 15) / 16;
    float sS[NT], sQ[NT];
#pragma unroll
    for (int nt = 0; nt < NT; ++nt) { sS[nt] = 0.f; sQ[nt] = 0.f; }

    for (int tile = wid; tile < ntile; tile += nw) {
        const int row0 = rfl(tile) * 16;
        int nr = nrows - row0;
        nr = nr > 16 ? 16 : nr;
        // ---- stage idx table (coalesced read, tap-major scatter, -1 pad) ----
        const int* src = nbr + (size_t)row0 * 27;
        const int tot = nr * 27;
        for (int t = lane; t < 432; t += 64) {
            int v = -1;
            if (t < tot) v = src[t];
            int r = t / 27;
            my[(t - r * 27) * 16 + r] = v;
        }
        float4e acc[NT];
#pragma unroll
        for (int nt = 0; nt < NT; ++nt) acc[nt] = (float4e)0.f;

        short8 gs[KT], gs2[KT];
        float4 gf[4], gf2[4];
        auto load_g = [&](int ir, short8 g[KT], float4 f[4]) {
            size_t id = (size_t)(ir < 0 ? 0 : ir);
            if (MODE == 0) {
                g[0] = *(const short8*)(inAb + id * 32 + q * 8);
            } else if (MODE == 2) {
                g[0] = *(const short8*)(inAb + id * 32 + q * 8);
                g[1] = *(const short8*)(inBb + id * 32 + q * 8);
            } else {
                const float* b = inAf + id * 64 + q * 8;
                f[0] = *(const float4*)(b);
                f[1] = *(const float4*)(b + 4);
                f[2] = *(const float4*)(b + 32);
                f[3] = *(const float4*)(b + 36);
            }
        };

        // ---- pipeline prologue: idx 2 ahead, gathers 1 ahead ----
        int irA = my[m15];        // tap 0
        int irB = my[16 + m15];   // tap 1
        int mA = rfl((int)(__ballot(irA >= 0) & 0xffff));
        if (mA) load_g(irA, gs, gf);
        for (int k = 0; k < 27; ++k) {
            int mB = rfl((int)(__ballot(irB >= 0) & 0xffff));
            int irC = -1;
            if (k + 2 < 27) irC = my[(k + 2) * 16 + m15];
            if (mB) load_g(irB, gs2, gf2);  // prefetch tap k+1 gathers
            if (mA) {
                short8 a[KT];
                if (MODE == 1) {
                    a[0] = cvt8(gf[0], gf[1]);
                    a[1] = cvt8(gf[2], gf[3]);
                } else {
#pragma unroll
                    for (int kt = 0; kt < KT; ++kt) a[kt] = gs[kt];
                }
                short8 z = (short8)(short)0;
#pragma unroll
                for (int kt = 0; kt < KT; ++kt) a[kt] = (irA >= 0) ? a[kt] : z;
                const short8* bp = (const short8*)Wp + (size_t)k * KT * NT * 64 + lane;
#pragma unroll
                for (int nt = 0; nt < NT; ++nt) {
#pragma unroll
                    for (int kt = 0; kt < KT; ++kt) {
                        short8 b = bp[(kt * NT + nt) * 64];
                        acc[nt] = __builtin_amdgcn_mfma_f32_16x16x32_bf16(a[kt], b, acc[nt], 0, 0, 0);
                    }
                }
            }
            mA = mB; irA = irB; irB = irC;
#pragma unroll
            for (int kt = 0; kt < KT; ++kt) gs[kt] = gs2[kt];
            if (MODE == 1) {
#pragma unroll
                for (int i = 0; i < 4; ++i) gf[i] = gf2[i];
            }
        }
        // ---- store C (col=lane&15, row=quad*4+reg) + BN stats ----
#pragma unroll
        for (int nt = 0; nt < NT; ++nt) {
#pragma unroll
            for (int r = 0; r < 4; ++r) {
                int rowg = row0 + q * 4 + r;
                if (rowg < nrows) {
                    float v = acc[nt][r];
                    stf(out + (size_t)rowg * COUT + nt * 16 + m15, v);
                    sS[nt] += v;
                    sQ[nt] += v * v;
                }
            }
        }
    }
    // ---- stats: reduce over quads (same col), one atomic per (col,nt) ----
#pragma unroll
    for (int nt = 0; nt < NT; ++nt) {
        float v = sS[nt], w = sQ[nt];
        v += __shfl_xor(v, 16); v += __shfl_xor(v, 32);
        w += __shfl_xor(w, 16); w += __shfl_xor(w, 32);
        if (lane < 16) {
            atomicAdd(&ssum[nt * 16 + lane], v);
            atomicAdd(&ssq[nt * 16 + lane], w);
        }
    }
}

// ---------------- BN finalize: scale/shift from sums ----------------
__global__ void k_fin(const float* __restrict__ ssum, const float* __restrict__ ssq,
                      const float* __restrict__ g, const float* __restrict__ b,
                      float* __restrict__ scale, float* __restrict__ shift,
                      int C, float invN) {
    int c = blockIdx.x * blockDim.x + threadIdx.x;
    if (c >= C) return;
    float mu = ssum[c] * invN;
    float var = fmaxf(ssq[c] * invN - mu * mu, 0.f);
    float s = g[c] * rsqrtf(var + BN_EPS);
    scale[c] = s;
    shift[c] = b[c] - mu * s;
}

// ---- e0 = bnrelu(e0raw) in place (bf16); down[parent] += e0 @ W_down[off] (fp32 atomics) ----
__global__ __launch_bounds__(256) void k_down(__hip_bfloat16* __restrict__ e0,
                                              const int* __restrict__ parent,
                                              const int* __restrict__ child,
                                              const float* __restrict__ Wd,
                                              const float* __restrict__ sc,
                                              const float* __restrict__ sh,
                                              float* __restrict__ down, int N) {
    const int lane = threadIdx.x & 63;
    int wid = blockIdx.x * 4 + (threadIdx.x >> 6);
    int nw = gridDim.x * 4;
    for (int row = wid; row < N; row += nw) {
        int urow = rfl(row);
        float v = 0.f;
        if (lane < 32) {
            float r = ldf(e0 + (size_t)urow * 32 + lane);
            v = fmaxf(fmaf(r, sc[lane], sh[lane]), 0.f);
            stf(e0 + (size_t)urow * 32 + lane, v);  // post-BN e0, consumed by dec
        }
        int par = rfl(parent[urow]);
        int off = rfl(child[urow]);
        float acc = 0.f;
        const float* wb = Wd + (size_t)off * 2048 + lane;  // W_down[off][c][lane]
#pragma unroll
        for (int c = 0; c < 32; ++c)
            acc = fmaf(__shfl(v, c), wb[c * 64], acc);
        atomicAdd(&down[(size_t)par * 64 + lane], acc);
    }
}

// ---- up[n] = bnrelu(e1raw)[parent[n]] @ W_up[off[n]] -> bf16 ----
__global__ __launch_bounds__(256) void k_up(const __hip_bfloat16* __restrict__ e1raw,
                                            const int* __restrict__ parent,
                                            const int* __restrict__ child,
                                            const float* __restrict__ Wu,
                                            const float* __restrict__ sc,
                                            const float* __restrict__ sh,
                                            __hip_bfloat16* __restrict__ up, int N) {
    const int lane = threadIdx.x & 63;
    int wid = blockIdx.x * 4 + (threadIdx.x >> 6);
    int nw = gridDim.x * 4;
    for (int row = wid; row < N; row += nw) {
        int urow = rfl(row);
        int par = rfl(parent[urow]);
        int off = rfl(child[urow]);
        float e = ldf(e1raw + (size_t)par * 64 + lane);
        float v = fmaxf(fmaf(e, sc[lane], sh[lane]), 0.f);  // BN on the fly
        int d = lane & 31, hi = lane >> 5;
        float acc = 0.f;
        const float* wb = Wu + (size_t)off * 2048 + (size_t)hi * 1024 + d;
#pragma unroll
        for (int c = 0; c < 32; ++c)
            acc = fmaf(__shfl(v, hi * 32 + c), wb[c * 32], acc);
        acc += __shfl_xor(acc, 32);
        if (hi == 0) stf(up + (size_t)urow * 32 + d, acc);
    }
}

// ---- feature = bnrelu(decraw); y = feature @ W_lin + b_lin ----
__global__ __launch_bounds__(256) void k_out(const __hip_bfloat16* __restrict__ dec,
                                             const float* __restrict__ sc,
                                             const float* __restrict__ sh,
                                             const float* __restrict__ Wl,
                                             const float* __restrict__ bl,
                                             float* __restrict__ y,
                                             float* __restrict__ feat, int N) {
    int n = blockIdx.x * 256 + threadIdx.x;
    if (n >= N) return;
    float f[32];
    const __hip_bfloat162* p = (const __hip_bfloat162*)(dec + (size_t)n * 32);
#pragma unroll
    for (int j = 0; j < 16; ++j) {
        float2 t = __bfloat1622float2(p[j]);
        f[2 * j + 0] = fmaxf(fmaf(t.x, sc[2 * j + 0], sh[2 * j + 0]), 0.f);
        f[2 * j + 1] = fmaxf(fmaf(t.y, sc[2 * j + 1], sh[2 * j + 1]), 0.f);
    }
    float4* fo = (float4*)(feat + (size_t)n * 32);
#pragma unroll
    for (int j = 0; j < 8; ++j)
        fo[j] = make_float4(f[4 * j], f[4 * j + 1], f[4 * j + 2], f[4 * j + 3]);
    float acc[20];
#pragma unroll
    for (int qq = 0; qq < 20; ++qq) acc[qq] = bl[qq];
#pragma unroll
    for (int c = 0; c < 32; ++c) {
        float fc = f[c];
#pragma unroll
        for (int qq = 0; qq < 20; ++qq) acc[qq] = fmaf(fc, Wl[c * 20 + qq], acc[qq]);
    }
    float4* yo = (float4*)(y + (size_t)n * 20);
#pragma unroll
    for (int j = 0; j < 5; ++j)
        yo[j] = make_float4(acc[4 * j], acc[4 * j + 1], acc[4 * j + 2], acc[4 * j + 3]);
}

extern "C" void kernel_launch(void* const* d_in, const int* in_sizes, int n_in,
                              void* d_out, int out_size, void* d_ws, size_t ws_size,
                              hipStream_t stream) {
    const float* feats = (const float*)d_in[0];
    const int* nbr_f   = (const int*)d_in[1];
    const int* nbr_c   = (const int*)d_in[2];
    const int* parent  = (const int*)d_in[3];
    const int* child   = (const int*)d_in[4];
    const float* W_sub = (const float*)d_in[5];
    const float* W_e0  = (const float*)d_in[6];
    const float* g0    = (const float*)d_in[7];
    const float* b0    = (const float*)d_in[8];
    const float* W_dn  = (const float*)d_in[9];
    const float* W_e1  = (const float*)d_in[10];
    const float* g1    = (const float*)d_in[11];
    const float* b1    = (const float*)d_in[12];
    const float* W_up  = (const float*)d_in[13];
    const float* W_dec = (const float*)d_in[14];
    const float* g_o   = (const float*)d_in[15];
    const float* b_o   = (const float*)d_in[16];
    const float* W_lin = (const float*)d_in[17];
    const float* b_lin = (const float*)d_in[18];

    const int N = in_sizes[0] / 3;
    const int M = in_sizes[2] / 27;

    // --- workspace: xvb bf16 [0..N*16 fl) (steps 3-4) / down fp32 [0..M*64 fl)
    // (steps 5-8) / up bf16 [0..N*16 fl) + decraw bf16 [N*16..N*32 fl)
    // (steps 10-13); stats at R ---
    float* wsf = (float*)d_ws;
    size_t R = (size_t)M * 64;
    if ((size_t)N * 32 > R) R = (size_t)N * 32;
    __hip_bfloat16* xvb = (__hip_bfloat16*)wsf;
    float* down = wsf;
    __hip_bfloat16* up     = (__hip_bfloat16*)wsf;
    __hip_bfloat16* decraw = (__hip_bfloat16*)(wsf + (size_t)N * 16);
    float* stats = wsf + R;
    // stats map: 0 sum0[32] | 32 sq0[32] | 64 sum1[64] | 128 sq1[64] |
    //            192 sumo[32] | 224 sqo[32] | 256 scale0 | 288 shift0 |
    //            320 scale1[64] | 384 shift1[64] | 448 scaleo | 480 shifto

    // --- d_out scratch: e0 bf16 [0..N*16 fl), e1raw bf16 [N*16..N*16+M*32 fl),
    // packed weights after; all dead before k_out writes y/feat ---
    __hip_bfloat16* e0    = (__hip_bfloat16*)d_out;
    __hip_bfloat16* e1raw = (__hip_bfloat16*)((float*)d_out + (size_t)N * 16);
    __hip_bfloat16* Wp0   = (__hip_bfloat16*)((float*)d_out + (size_t)N * 16 + (size_t)M * 32);
    const int T0 = 27 * 1 * 2 * 512;  // e0 pack: KT1 NT2
    const int T1 = 27 * 2 * 4 * 512;  // e1 pack: KT2 NT4
    const int T2 = 27 * 2 * 2 * 512;  // dec pack: KT2 NT2
    __hip_bfloat16* Wp1 = Wp0 + T0;
    __hip_bfloat16* Wp2 = Wp1 + T1;
    float* y    = (float*)d_out;
    float* feat = y + (size_t)N * 20;

    const int nblk = (N + 255) / 256;
    const int G = 2048;

    hipMemsetAsync(stats, 0, 256 * sizeof(float), stream);
    k_pack<<<(T0 + 255) / 256, 256, 0, stream>>>(W_e0, Wp0, 32, 32, 1, 2, T0);
    k_pack<<<(T1 + 255) / 256, 256, 0, stream>>>(W_e1, Wp1, 64, 64, 2, 4, T1);
    k_pack<<<(T2 + 255) / 256, 256, 0, stream>>>(W_dec, Wp2, 64, 32, 2, 2, T2);

    k_xv<<<nblk, 256, 0, stream>>>(feats, nbr_f, W_sub, xvb, N);
    k_conv<32, 32, 0><<<G, 256, 0, stream>>>(xvb, nullptr, nbr_f, Wp0, e0, N,
                                             stats + 0, stats + 32);
    // xvb dead; zero `down` (same region) for the atomic segment-sum
    hipMemsetAsync(down, 0, (size_t)M * 64 * sizeof(float), stream);
    k_fin<<<1, 64, 0, stream>>>(stats + 0, stats + 32, g0, b0,
                                stats + 256, stats + 288, 32, 1.f / (float)N);
    k_down<<<G, 256, 0, stream>>>(e0, parent, child, W_dn,
                                  stats + 256, stats + 288, down, N);
    k_conv<64, 64, 1><<<G, 256, 0, stream>>>(down, nullptr, nbr_c, Wp1, e1raw, M,
                                             stats + 64, stats + 128);
    k_fin<<<1, 64, 0, stream>>>(stats + 64, stats + 128, g1, b1,
                                stats + 320, stats + 384, 64, 1.f / (float)M);
    k_up<<<G, 256, 0, stream>>>(e1raw, parent, child, W_up,
                                stats + 320, stats + 384, up, N);
    k_conv<64, 32, 2><<<G, 256, 0, stream>>>(e0, up, nbr_f, Wp2, decraw, N,
                                             stats + 192, stats + 224);
    k_fin<<<1, 64, 0, stream>>>(stats + 192, stats + 224, g_o, b_o,
                                stats + 448, stats + 480, 32, 1.f / (float)N);
    k_out<<<nblk, 256, 0, stream>>>(decraw, stats + 448, stats + 480, W_lin, b_lin,
                                    y, feat, N);
}